// Round 12
// baseline (299.613 us; speedup 1.0000x reference)
//
#include <hip/hip_runtime.h>
#include <math.h>

#define NB 32    // batch
#define NS 128   // steps
#define NI 256   // in_dim
#define NC 128   // num capsules
#define ND 64    // dim capsule

#define L4 9.210340371976184f  // ln(10000)
#define NBLK 256
#define NTHR 1024

// ~88 KB LDS (>80 KB -> exactly 1 block/CU, all 256 blocks co-resident)
struct ShR {
    float  cs[4][NS][2];        // 4 KB
    float  Us[4][NS][2];        // 4 KB
    float4 redw[4][2][4][16];   // 8 KB
    float4 outs4[4][2][16];     // 2 KB
    float  tpar[4][2][2];
    float  sc2[4][2][2];        // [su][bh][{scale,PUu}]
    float  red2[4][2][NS * 17]; // 68 KB
};

// device-scope grid barrier: atomic arrive + agent-scope spin; __threadfence
// emits the gfx94x buffer_wbl2/inv pair so cross-XCD data is visible (G16).
__device__ __forceinline__ void gbar(int* bar, int idx) {
    __syncthreads();
    if (threadIdx.x == 0) {
        __threadfence();
        atomicAdd(&bar[idx], 1);
        while (__hip_atomic_load(&bar[idx], __ATOMIC_RELAXED,
                                 __HIP_MEMORY_SCOPE_AGENT) < NBLK) {
            __builtin_amdgcn_s_sleep(8);
        }
        __threadfence();
    }
    __syncthreads();
}

// one routing unit = (b-pair, n), executed by sub-block su (256 threads tt).
// v7 structure: pass1 acc += c*(M+pe2-rotation); squash; pass2 recompute.
__device__ void route_unit(int un, int tt, int su,
                           const float* __restrict__ M,
                           const float* __restrict__ U,
                           const float* __restrict__ cg,
                           const float* __restrict__ mask,
                           float* __restrict__ og,
                           float* __restrict__ bl,
                           int first, int last, ShR* sh) {
    int n  = un & 127;
    int b0 = (un >> 7) * 2;

    __syncthreads();   // protect LDS reuse across sequential units

    {   // staging: c, U, T2 = sum_s c*U
        int bh = tt >> 7, s = tt & 127;
        int b = b0 + bh;
        float uu = U[b * NS + s];
        float cv = first ? mask[b * NS + s] * (1.f / 128.f)
                         : cg[(b * NC + n) * NS + s];
        sh->cs[su][s][bh] = cv;
        sh->Us[su][s][bh] = uu;
        float p = cv * uu;
#pragma unroll
        for (int o = 32; o > 0; o >>= 1) p += __shfl_xor(p, o);
        if ((tt & 63) == 0) sh->tpar[su][bh][(tt >> 6) & 1] = p;
    }

    int dq = tt & 15, sq = tt >> 4;
    int s0 = sq * 8;
    int k2 = n * 32 + dq * 2;
    float g0 = __expf(-L4 * (float)k2 * (1.f / 4096.f));
    float g1 = __expf(-L4 * (float)(k2 + 1) * (1.f / 4096.f));
    float sg0 = __sinf(g0), cg0_ = __cosf(g0);
    float sg1 = __sinf(g1), cg1_ = __cosf(g1);
    float sa = __sinf((float)s0 * g0), ca = __cosf((float)s0 * g0);
    float sb = __sinf((float)s0 * g1), cb = __cosf((float)s0 * g1);
    __syncthreads();

    const float4* M4a = (const float4*)(M + (size_t)(b0 * NS) * ND) + dq;
    const float4* M4b = M4a + NS * 16;
    float4 acc0 = make_float4(0.f, 0.f, 0.f, 0.f);
    float4 acc1 = make_float4(0.f, 0.f, 0.f, 0.f);
#pragma unroll
    for (int i = 0; i < 8; ++i) {
        int s = s0 + i;
        float4 m0 = M4a[s * 16];
        float4 m1 = M4b[s * 16];
        float2 cc = *(const float2*)&sh->cs[su][s][0];
        acc0.x = fmaf(cc.x, m0.x + sa, acc0.x);
        acc0.y = fmaf(cc.x, m0.y + ca, acc0.y);
        acc0.z = fmaf(cc.x, m0.z + sb, acc0.z);
        acc0.w = fmaf(cc.x, m0.w + cb, acc0.w);
        acc1.x = fmaf(cc.y, m1.x + sa, acc1.x);
        acc1.y = fmaf(cc.y, m1.y + ca, acc1.y);
        acc1.z = fmaf(cc.y, m1.z + sb, acc1.z);
        acc1.w = fmaf(cc.y, m1.w + cb, acc1.w);
        float nsa = fmaf(sa, cg0_, ca * sg0);
        float nca = fmaf(ca, cg0_, -sa * sg0);
        sa = nsa; ca = nca;
        float nsb = fmaf(sb, cg1_, cb * sg1);
        float ncb = fmaf(cb, cg1_, -sb * sg1);
        sb = nsb; cb = ncb;
    }
#pragma unroll
    for (int o = 16; o <= 32; o <<= 1) {
        acc0.x += __shfl_xor(acc0.x, o); acc0.y += __shfl_xor(acc0.y, o);
        acc0.z += __shfl_xor(acc0.z, o); acc0.w += __shfl_xor(acc0.w, o);
        acc1.x += __shfl_xor(acc1.x, o); acc1.y += __shfl_xor(acc1.y, o);
        acc1.z += __shfl_xor(acc1.z, o); acc1.w += __shfl_xor(acc1.w, o);
    }
    if ((tt & 48) == 0) {
        int w = tt >> 6;
        sh->redw[su][0][w][dq] = acc0;
        sh->redw[su][1][w][dq] = acc1;
    }
    __syncthreads();

    // combine + squash (lanes 0-31 of su's first wave); PE1 computed inline
    if (tt < 32) {
        int bh = tt >> 4, q = tt & 15;
        float4 r0 = sh->redw[su][bh][0][q], r1 = sh->redw[su][bh][1][q];
        float4 r2 = sh->redw[su][bh][2][q], r3 = sh->redw[su][bh][3][q];
        float4 o;
        o.x = r0.x + r1.x + r2.x + r3.x;
        o.y = r0.y + r1.y + r2.y + r3.y;
        o.z = r0.z + r1.z + r2.z + r3.z;
        o.w = r0.w + r1.w + r2.w + r3.w;
        float T2 = sh->tpar[su][bh][0] + sh->tpar[su][bh][1];
        float fa = __expf(-L4 * (float)(2 * q) * (1.f / 32.f));
        float fb = __expf(-L4 * (float)(2 * q + 1) * (1.f / 32.f));
        float a1 = (float)n * fa, a2 = (float)n * fb;
        float4 p14 = make_float4(__sinf(a1), __cosf(a1), __sinf(a2), __cosf(a2));
        o.x = fmaf(p14.x, T2, o.x);
        o.y = fmaf(p14.y, T2, o.y);
        o.z = fmaf(p14.z, T2, o.z);
        o.w = fmaf(p14.w, T2, o.w);
        sh->outs4[su][bh][q] = o;
        float ssq = o.x * o.x + o.y * o.y + o.z * o.z + o.w * o.w;
        float ppu = o.x * p14.x + o.y * p14.y + o.z * p14.z + o.w * p14.w;
#pragma unroll
        for (int o2 = 1; o2 <= 8; o2 <<= 1) {
            ssq += __shfl_xor(ssq, o2);
            ppu += __shfl_xor(ppu, o2);
        }
        if (q == 0) {
            sh->sc2[su][bh][0] = ssq / (1.f + ssq) * rsqrtf(ssq + 1e-7f);
            sh->sc2[su][bh][1] = ppu;
        }
    }
    __syncthreads();

    if (last) {
        if (tt < 32) {
            int bh = tt >> 4, q = tt & 15;
            float sc = sh->sc2[su][bh][0];
            float4 o = sh->outs4[su][bh][q];
            o.x *= sc; o.y *= sc; o.z *= sc; o.w *= sc;
            ((float4*)og)[((b0 + bh) * NC + n) * 16 + q] = o;
        }
        return;
    }

    // pass 2: rebuild u-hat (M reload, L1-hot + fresh rotation), dot, reduce
    float sa2 = __sinf((float)s0 * g0), ca2 = __cosf((float)s0 * g0);
    float sb2 = __sinf((float)s0 * g1), cb2 = __cosf((float)s0 * g1);
    float4 oa = sh->outs4[su][0][dq], ob = sh->outs4[su][1][dq];
#pragma unroll
    for (int i = 0; i < 8; ++i) {
        int s = s0 + i;
        float4 m0 = M4a[s * 16];
        float4 m1 = M4b[s * 16];
        sh->red2[su][0][s * 17 + dq] =
            (m0.x + sa2) * oa.x + (m0.y + ca2) * oa.y +
            (m0.z + sb2) * oa.z + (m0.w + cb2) * oa.w;
        sh->red2[su][1][s * 17 + dq] =
            (m1.x + sa2) * ob.x + (m1.y + ca2) * ob.y +
            (m1.z + sb2) * ob.z + (m1.w + cb2) * ob.w;
        float nsa = fmaf(sa2, cg0_, ca2 * sg0);
        float nca = fmaf(ca2, cg0_, -sa2 * sg0);
        sa2 = nsa; ca2 = nca;
        float nsb = fmaf(sb2, cg1_, cb2 * sg1);
        float ncb = fmaf(cb2, cg1_, -sb2 * sg1);
        sb2 = nsb; cb2 = ncb;
    }
    __syncthreads();
    {
        int bh = tt >> 7, s = tt & 127;
        const float* r = &sh->red2[su][bh][s * 17];
        float sum = 0.f;
#pragma unroll
        for (int q = 0; q < 16; ++q) sum += r[q];
        bl[((b0 + bh) * NC + n) * NS + s] =
            sh->sc2[su][bh][0] * (sum + sh->sc2[su][bh][1] * sh->Us[su][s][bh]);
    }
}

// ---------------------------------------------------------------------------
// mega: entire pipeline in ONE kernel. 256 blocks x 1024 threads, 5 grid
// barriers. Phases: prep -> [route, softmax] x2 -> route-final.
// ---------------------------------------------------------------------------
__global__ __launch_bounds__(NTHR) void mega(const float* __restrict__ u,
                                             const float* __restrict__ W,
                                             const float* __restrict__ mask,
                                             float* __restrict__ M,
                                             float* __restrict__ U,
                                             float* __restrict__ c,
                                             float* __restrict__ bl,
                                             float* __restrict__ og,
                                             int* __restrict__ bar) {
    __shared__ ShR sh;
    int t = threadIdx.x;
    int blk = blockIdx.x;
    int su = t >> 8, tt = t & 255;

    // ---- P0: prep  M[b,s,d] = sum_i u*W ; U[b,s] = sum_i u ----
    {
        int row = blk * 16 + (t >> 6);   // 4096 rows over 256 blocks
        int d = t & 63;
        const float* ur = u + row * NI;
        float acc = 0.f, rs = 0.f;
#pragma unroll 4
        for (int i = 0; i < NI; ++i) {
            float v = ur[i];
            acc = fmaf(v, W[i * ND + d], acc);
            rs += v;
        }
        M[row * ND + d] = acc;
        if (d == 0) U[row] = rs;
    }
    gbar(bar, 0);

    // ---- P1: iter0 route (first=1) ----
    for (int r = 0; r < 2; ++r)
        route_unit(blk * 8 + r * 4 + su, tt, su, M, U, c, mask, og, bl, 1, 0, &sh);
    gbar(bar, 1);

    // ---- P2: softmax over n; one wave per (b,s) row ----
    {
        int row = blk * 16 + (t >> 6);   // 4096 rows
        int b = row >> 7, s = row & 127;
        int l = t & 63;
        float v1 = bl[(b * NC + l) * NS + s];
        float v2 = bl[(b * NC + l + 64) * NS + s];
        float mx = fmaxf(v1, v2);
#pragma unroll
        for (int o = 32; o > 0; o >>= 1) mx = fmaxf(mx, __shfl_xor(mx, o));
        float e1 = __expf(v1 - mx), e2 = __expf(v2 - mx);
        float sm = e1 + e2;
#pragma unroll
        for (int o = 32; o > 0; o >>= 1) sm += __shfl_xor(sm, o);
        float f = mask[b * NS + s] / sm;
        c[(b * NC + l) * NS + s] = e1 * f;
        c[(b * NC + l + 64) * NS + s] = e2 * f;
    }
    gbar(bar, 2);

    // ---- P3: iter1 route ----
    for (int r = 0; r < 2; ++r)
        route_unit(blk * 8 + r * 4 + su, tt, su, M, U, c, mask, og, bl, 0, 0, &sh);
    gbar(bar, 3);

    // ---- P4: softmax ----
    {
        int row = blk * 16 + (t >> 6);
        int b = row >> 7, s = row & 127;
        int l = t & 63;
        float v1 = bl[(b * NC + l) * NS + s];
        float v2 = bl[(b * NC + l + 64) * NS + s];
        float mx = fmaxf(v1, v2);
#pragma unroll
        for (int o = 32; o > 0; o >>= 1) mx = fmaxf(mx, __shfl_xor(mx, o));
        float e1 = __expf(v1 - mx), e2 = __expf(v2 - mx);
        float sm = e1 + e2;
#pragma unroll
        for (int o = 32; o > 0; o >>= 1) sm += __shfl_xor(sm, o);
        float f = mask[b * NS + s] / sm;
        c[(b * NC + l) * NS + s] = e1 * f;
        c[(b * NC + l + 64) * NS + s] = e2 * f;
    }
    gbar(bar, 4);

    // ---- P5: iter2 route (last=1) -> d_out ----
    for (int r = 0; r < 2; ++r)
        route_unit(blk * 8 + r * 4 + su, tt, su, M, U, c, mask, og, bl, 0, 1, &sh);
}

// ---------------------------------------------------------------------------
extern "C" void kernel_launch(void* const* d_in, const int* in_sizes, int n_in,
                              void* d_out, int out_size, void* d_ws, size_t ws_size,
                              hipStream_t stream) {
    const float* u    = (const float*)d_in[0];  // (32,128,256)
    const float* mask = (const float*)d_in[1];  // (32,128)
    const float* W    = (const float*)d_in[2];  // (1,256,64)
    float* out = (float*)d_out;                 // (32,128,64) = [b][n][d]

    int*   bar = (int*)d_ws;                    // 16 ints (64 B)
    float* base = (float*)d_ws + 16;
    float* M  = base;                           // 262144
    float* U  = M + NB * NS * ND;               // 4096
    float* c  = U + NB * NS;                    // 524288  [b][n][s]
    float* bl = c + NB * NC * NS;               // 524288  [b][n][s]

    hipMemsetAsync(d_ws, 0, 64, stream);        // zero barrier counters
    mega<<<NBLK, NTHR, 0, stream>>>(u, W, mask, M, U, c, bl, out, bar);
}

// Round 13
// 114.963 us; speedup vs baseline: 2.6062x; 2.6062x over previous
//
#include <hip/hip_runtime.h>
#include <math.h>

#define NB 32    // batch
#define NS 128   // steps
#define NI 256   // in_dim
#define NC 128   // num capsules
#define ND 64    // dim capsule

#define L4 9.210340371976184f  // ln(10000)

// ---------------------------------------------------------------------------
// k_prep:
//   blocks [0,1024):      M[b,s,d] = sum_i u*W ; U[b,s] = sum_i u
//   blocks [1024,1056):   PE1[n][d]
// ---------------------------------------------------------------------------
__global__ __launch_bounds__(256) void k_prep(const float* __restrict__ u,
                                              const float* __restrict__ W,
                                              float* __restrict__ M,
                                              float* __restrict__ U,
                                              float* __restrict__ PE1) {
    int blk = blockIdx.x;
    int t = threadIdx.x;
    if (blk < 1024) {
        int row = blk * 4 + (t >> 6);   // b*NS + s
        int d = t & 63;
        const float* ur = u + row * NI;
        float acc = 0.f, rs = 0.f;
#pragma unroll 4
        for (int i = 0; i < NI; ++i) {
            float v = ur[i];
            acc = fmaf(v, W[i * ND + d], acc);
            rs += v;
        }
        M[row * ND + d] = acc;
        if (d == 0) U[row] = rs;
    } else {
        int idx = (blk - 1024) * 256 + t;   // 8192 elems, [n][d]
        int n = idx >> 6, d = idx & 63;
        float ang = (float)n * __expf(-L4 * (float)(d >> 1) * (1.f / 32.f));
        float sv, cv;
        __sincosf(ang, &sv, &cv);
        PE1[idx] = (d & 1) ? cv : sv;
    }
}

// ---------------------------------------------------------------------------
// kR v8: R10's v6 (best: 2048 blocks, (b-pair, n), retained u-hat) with the
// serial front removed: c/U staged in REGISTERS (redundant dq-loads hit L1
// broadcast), so all VMEM (16 M-loads + 4 c-loads) issues at kernel start
// with no barrier. 'first' scaling folded into squash (c linear in both
// contractions). T2 on a parallel 128-thread path. 3 barriers (was 4).
// ~20 KB LDS, launch_bounds(256,4).
// ---------------------------------------------------------------------------
__global__ __launch_bounds__(256, 4) void kR(const float* __restrict__ M,
                                             const float* __restrict__ U,
                                             const float* __restrict__ PE1,
                                             const float* __restrict__ cg,
                                             const float* __restrict__ mask,
                                             float* __restrict__ og,
                                             float* __restrict__ bl,
                                             int first, int last) {
    int bp = blockIdx.x;                // (b-pair)*128 + n
    int n  = bp & 127;
    int b0 = (bp >> 7) * 2;
    int t  = threadIdx.x;

    __shared__ float4 redw[2][4][16];   // 2 KB
    __shared__ float4 outs4[2][16];     // 512 B
    __shared__ float  tpar[2][2];
    __shared__ float  sc2[2][2];        // [bh][{scale, PUu}]
    __shared__ float  red2[2][NS * 17]; // 17408 B

    int dq = t & 15, sq = t >> 4;
    int s0 = sq * 8;

    // c rows (raw mask on first iter; scaling folded into squash)
    const float* cr0 = first ? (mask + b0 * NS)
                             : (cg + ((size_t)(b0 * NC + n)) * NS);
    const float* cr1 = first ? (mask + (b0 + 1) * NS)
                             : (cg + ((size_t)((b0 + 1) * NC + n)) * NS);

    // per-thread c fragments (8 consecutive s, both batches) — issue early
    float4 c0a = *(const float4*)(cr0 + s0);
    float4 c0b = *(const float4*)(cr0 + s0 + 4);
    float4 c1a = *(const float4*)(cr1 + s0);
    float4 c1b = *(const float4*)(cr1 + s0 + 4);

    // pe2 frequencies for (n, dq) — shared by both batches
    int k2 = n * 32 + dq * 2;
    float g0 = __expf(-L4 * (float)k2 * (1.f / 4096.f));
    float g1 = __expf(-L4 * (float)(k2 + 1) * (1.f / 4096.f));
    float sg0 = __sinf(g0), cg0 = __cosf(g0);
    float sg1 = __sinf(g1), cg1 = __cosf(g1);
    float sa = __sinf((float)s0 * g0), ca = __cosf((float)s0 * g0);
    float sb = __sinf((float)s0 * g1), cb = __cosf((float)s0 * g1);

    // ---- pass 1 (no barrier before): u-hat in registers, acc += c*uh ----
    const float4* M4a = (const float4*)(M + (size_t)(b0 * NS) * ND) + dq;
    const float4* M4b = M4a + NS * 16;
    float4 va[8], vb[8];
    float4 acc0 = make_float4(0.f, 0.f, 0.f, 0.f);
    float4 acc1 = make_float4(0.f, 0.f, 0.f, 0.f);
#pragma unroll
    for (int i = 0; i < 8; ++i) {
        int s = s0 + i;
        float4 m0 = M4a[s * 16];
        float4 m1 = M4b[s * 16];
        float cc0 = (i < 4) ? ((const float*)&c0a)[i & 3] : ((const float*)&c0b)[i & 3];
        float cc1 = (i < 4) ? ((const float*)&c1a)[i & 3] : ((const float*)&c1b)[i & 3];
        float4 u0, u1;
        u0.x = m0.x + sa; u0.y = m0.y + ca; u0.z = m0.z + sb; u0.w = m0.w + cb;
        u1.x = m1.x + sa; u1.y = m1.y + ca; u1.z = m1.z + sb; u1.w = m1.w + cb;
        va[i] = u0; vb[i] = u1;
        acc0.x = fmaf(cc0, u0.x, acc0.x);
        acc0.y = fmaf(cc0, u0.y, acc0.y);
        acc0.z = fmaf(cc0, u0.z, acc0.z);
        acc0.w = fmaf(cc0, u0.w, acc0.w);
        acc1.x = fmaf(cc1, u1.x, acc1.x);
        acc1.y = fmaf(cc1, u1.y, acc1.y);
        acc1.z = fmaf(cc1, u1.z, acc1.z);
        acc1.w = fmaf(cc1, u1.w, acc1.w);
        float nsa = fmaf(sa, cg0, ca * sg0);
        float nca = fmaf(ca, cg0, -sa * sg0);
        sa = nsa; ca = nca;
        float nsb = fmaf(sb, cg1, cb * sg1);
        float ncb = fmaf(cb, cg1, -sb * sg1);
        sb = nsb; cb = ncb;
    }
    // reduce the 4 sq-chunks within each wave (lanes xor 16, 32)
#pragma unroll
    for (int o = 16; o <= 32; o <<= 1) {
        acc0.x += __shfl_xor(acc0.x, o); acc0.y += __shfl_xor(acc0.y, o);
        acc0.z += __shfl_xor(acc0.z, o); acc0.w += __shfl_xor(acc0.w, o);
        acc1.x += __shfl_xor(acc1.x, o); acc1.y += __shfl_xor(acc1.y, o);
        acc1.z += __shfl_xor(acc1.z, o); acc1.w += __shfl_xor(acc1.w, o);
    }
    if ((t & 48) == 0) {
        int w = t >> 6;
        redw[0][w][dq] = acc0;
        redw[1][w][dq] = acc1;
    }
    // ---- T2[bh] = sum_s c*U, parallel path on threads 0-255 (overlaps) ----
    {
        int bh = t >> 7, s = t & 127;
        const float* cr = bh ? cr1 : cr0;
        float p = cr[s] * U[(b0 + bh) * NS + s];
#pragma unroll
        for (int o = 32; o > 0; o >>= 1) p += __shfl_xor(p, o);
        if ((t & 63) == 0) tpar[bh][(t >> 6) & 1] = p;
    }
    __syncthreads();

    // ---- combine + squash (lanes 0-31; 'first' scaling applied here) ----
    if (t < 32) {
        int bh = t >> 4, q = t & 15;
        float4 r0 = redw[bh][0][q], r1 = redw[bh][1][q];
        float4 r2 = redw[bh][2][q], r3 = redw[bh][3][q];
        float4 o;
        o.x = r0.x + r1.x + r2.x + r3.x;
        o.y = r0.y + r1.y + r2.y + r3.y;
        o.z = r0.z + r1.z + r2.z + r3.z;
        o.w = r0.w + r1.w + r2.w + r3.w;
        float T2 = tpar[bh][0] + tpar[bh][1];
        float4 p14 = ((const float4*)PE1)[n * 16 + q];
        o.x = fmaf(p14.x, T2, o.x);
        o.y = fmaf(p14.y, T2, o.y);
        o.z = fmaf(p14.z, T2, o.z);
        o.w = fmaf(p14.w, T2, o.w);
        if (first) { o.x *= (1.f / 128.f); o.y *= (1.f / 128.f);
                     o.z *= (1.f / 128.f); o.w *= (1.f / 128.f); }
        outs4[bh][q] = o;
        float ssq = o.x * o.x + o.y * o.y + o.z * o.z + o.w * o.w;
        float ppu = o.x * p14.x + o.y * p14.y + o.z * p14.z + o.w * p14.w;
#pragma unroll
        for (int o2 = 1; o2 <= 8; o2 <<= 1) {   // within 16-lane group
            ssq += __shfl_xor(ssq, o2);
            ppu += __shfl_xor(ppu, o2);
        }
        if (q == 0) {
            sc2[bh][0] = ssq / (1.f + ssq) * rsqrtf(ssq + 1e-7f);
            sc2[bh][1] = ppu;
        }
    }
    __syncthreads();

    if (last) {
        if (t < 32) {
            int bh = t >> 4, q = t & 15;
            float sc = sc2[bh][0];
            float4 o = outs4[bh][q];
            o.x *= sc; o.y *= sc; o.z *= sc; o.w *= sc;
            ((float4*)og)[((b0 + bh) * NC + n) * 16 + q] = o;
        }
        return;
    }

    // ---- pass 2: dot retained u-hat with outs4, LDS partial, reduce ----
    float4 oa = outs4[0][dq], ob = outs4[1][dq];
#pragma unroll
    for (int i = 0; i < 8; ++i) {
        int s = s0 + i;
        float4 v0 = va[i], v1 = vb[i];
        red2[0][s * 17 + dq] = v0.x * oa.x + v0.y * oa.y + v0.z * oa.z + v0.w * oa.w;
        red2[1][s * 17 + dq] = v1.x * ob.x + v1.y * ob.y + v1.z * ob.z + v1.w * ob.w;
    }
    __syncthreads();
    {
        int bh = t >> 7, s = t & 127;
        const float* r = &red2[bh][s * 17];
        float sum = 0.f;
#pragma unroll
        for (int q = 0; q < 16; ++q) sum += r[q];
        bl[((b0 + bh) * NC + n) * NS + s] =
            sc2[bh][0] * (sum + sc2[bh][1] * U[(b0 + bh) * NS + s]);
    }
}

// ---------------------------------------------------------------------------
// kS v2: softmax over n for each (b,s); c[b,n,s] = softmax_n(bl)*mask.
// bl/c layout [b][n][s]. Block = (b, 8-s tile), 256 thr, grid = 512.
// ---------------------------------------------------------------------------
__global__ __launch_bounds__(256) void kS(const float* __restrict__ bl,
                                          const float* __restrict__ mask,
                                          float* __restrict__ c) {
    int blk = blockIdx.x;
    int b = blk >> 4, s0 = (blk & 15) * 8;
    int t = threadIdx.x;

    __shared__ float tl[NC][9];
    __shared__ float pr[32][9];
    __shared__ float ps[32][9];
    __shared__ float itot[8], msk[8];

    if (t < 8) msk[t] = mask[b * NS + s0 + t];
#pragma unroll
    for (int i = 0; i < 4; ++i) {
        int idx = i * 256 + t;
        int n = idx >> 3, si = idx & 7;
        tl[n][si] = bl[(b * NC + n) * NS + s0 + si];
    }
    __syncthreads();

    int si = t & 7, ch = t >> 3;       // 32 chunks x 4 n each
    float mx = -1e30f;
#pragma unroll
    for (int j = 0; j < 4; ++j) mx = fmaxf(mx, tl[ch * 4 + j][si]);
    pr[ch][si] = mx;
    __syncthreads();

    mx = pr[0][si];
#pragma unroll
    for (int jc = 1; jc < 32; ++jc) mx = fmaxf(mx, pr[jc][si]);
    float sm = 0.f;
#pragma unroll
    for (int j = 0; j < 4; ++j) {
        float e = __expf(tl[ch * 4 + j][si] - mx);
        tl[ch * 4 + j][si] = e;        // owner-exclusive rows: no race
        sm += e;
    }
    ps[ch][si] = sm;
    __syncthreads();

    if (t < 8) {
        float tot = 0.f;
#pragma unroll
        for (int jc = 0; jc < 32; ++jc) tot += ps[jc][t];
        itot[t] = msk[t] / tot;
    }
    __syncthreads();

#pragma unroll
    for (int i = 0; i < 4; ++i) {
        int idx = i * 256 + t;
        int n = idx >> 3, sj = idx & 7;
        c[(b * NC + n) * NS + s0 + sj] = tl[n][sj] * itot[sj];
    }
}

// ---------------------------------------------------------------------------
extern "C" void kernel_launch(void* const* d_in, const int* in_sizes, int n_in,
                              void* d_out, int out_size, void* d_ws, size_t ws_size,
                              hipStream_t stream) {
    const float* u    = (const float*)d_in[0];  // (32,128,256)
    const float* mask = (const float*)d_in[1];  // (32,128)
    const float* W    = (const float*)d_in[2];  // (1,256,64)
    float* out = (float*)d_out;                 // (32,128,64) = [b][n][d]

    float* ws  = (float*)d_ws;
    float* M   = ws;                            // 262144
    float* U   = M + NB * NS * ND;              // 4096
    float* PE1 = U + NB * NS;                   // 8192
    float* c   = PE1 + NC * ND;                 // 524288  [b][n][s]
    float* bl  = c + NB * NC * NS;              // 524288  [b][n][s]

    k_prep<<<1056, 256, 0, stream>>>(u, W, M, U, PE1);

    // iter 0 (uniform c = mask/128, folded into squash) -> logits bl
    kR<<<2048, 256, 0, stream>>>(M, U, PE1, c, mask, out, bl, 1, 0);
    kS<<<512, 256, 0, stream>>>(bl, mask, c);
    // iter 1 -> logits bl
    kR<<<2048, 256, 0, stream>>>(M, U, PE1, c, mask, out, bl, 0, 0);
    kS<<<512, 256, 0, stream>>>(bl, mask, c);
    // iter 2 (final) -> d_out
    kR<<<2048, 256, 0, stream>>>(M, U, PE1, c, mask, out, bl, 0, 1);
}